// Round 7
// baseline (334.684 us; speedup 1.0000x reference)
//
#include <hip/hip_runtime.h>

// Problem constants
#define NND 10000      // nodes
#define NED 160000     // edges (before self loops)
#define NET 170000     // edges incl self loops
#define MP  10112      // node rows padded to multiple of 128 (79*128)
#define DH  1024       // H*C hidden width
#define DIN 512
#define DOUT 512
#define SCB 40         // scan blocks: ceil(NND/256)

// prep kernel block ranges
#define NB_CONV 5056   // MP*DIN/4/256
#define NB_T1   512    // (DH/32)*(DIN/32)
#define NB_T2   1024   // (DH/32)*(DH/32)
#define NB_T3   512    // (DOUT/32)*(DH/32)
#define NB_Z    80
#define NB_PREP (NB_CONV + NB_T1 + NB_T2 + NB_T3 + NB_Z)

typedef unsigned short u16;
typedef __attribute__((ext_vector_type(8))) short short8_t;
typedef __attribute__((ext_vector_type(4))) float f32x4_t;

__device__ __forceinline__ u16 f2bf(float f) {
  unsigned u = __float_as_uint(f);
  return (u16)((u + 0x7fffu + ((u >> 16) & 1u)) >> 16);
}
__device__ __forceinline__ float bf2f(u16 b) {
  return __uint_as_float(((unsigned)b) << 16);
}
__device__ __forceinline__ float bflo(unsigned u) { return __uint_as_float(u << 16); }
__device__ __forceinline__ float bfhi(unsigned u) { return __uint_as_float(u & 0xffff0000u); }
__device__ __forceinline__ float lrelu(float v) { return v > 0.f ? v : 0.2f * v; }

// async global->LDS, 16B per lane. LDS dest must be linear (uniform base + lane*16).
__device__ __forceinline__ void gl_lds16(const void* g, void* l) {
  __builtin_amdgcn_global_load_lds(
      (const __attribute__((address_space(1))) unsigned int*)g,
      (__attribute__((address_space(3))) unsigned int*)l, 16, 0, 0);
}

// ---------------- merged prep: x->bf16, 3 weight transposes, zeroing ----------------

__device__ __forceinline__ void dev_transpose(const float* __restrict__ W,
                                              u16* __restrict__ WT,
                                              int K, int Nt, int bx, int by, int t) {
  __shared__ float s[32][33];
  const int kt = by * 32, nt = bx * 32;
  const int tx = t & 31, ty = t >> 5;   // (32,8)
#pragma unroll
  for (int i = 0; i < 32; i += 8)
    s[ty + i][tx] = W[(size_t)(kt + ty + i) * Nt + nt + tx];
  __syncthreads();
#pragma unroll
  for (int i = 0; i < 32; i += 8)
    WT[(size_t)(nt + ty + i) * K + kt + tx] = f2bf(s[tx][ty + i]);
}

__global__ void k_prep(const float* __restrict__ x, u16* __restrict__ xb,
                       const float* __restrict__ W1, u16* __restrict__ w1t,
                       const float* __restrict__ W2, u16* __restrict__ w2t,
                       const float* __restrict__ Wfc, u16* __restrict__ wft,
                       int* __restrict__ indeg,
                       u16* __restrict__ hbp, u16* __restrict__ h2bp) {
  int b = blockIdx.x, t = threadIdx.x;
  if (b < NB_CONV) {
    int i = b * 256 + t;
    float4 v = make_float4(0.f, 0.f, 0.f, 0.f);
    if (i < NND * DIN / 4) v = ((const float4*)x)[i];
    ushort4 o;
    o.x = f2bf(v.x); o.y = f2bf(v.y); o.z = f2bf(v.z); o.w = f2bf(v.w);
    ((ushort4*)xb)[i] = o;
    return;
  }
  b -= NB_CONV;
  if (b < NB_T1) { dev_transpose(W1, w1t, DIN, DH, b & 31, b >> 5, t); return; }
  b -= NB_T1;
  if (b < NB_T2) { dev_transpose(W2, w2t, DH, DH, b & 31, b >> 5, t); return; }
  b -= NB_T2;
  if (b < NB_T3) { dev_transpose(Wfc, wft, DH, DOUT, b & 15, b >> 4, t); return; }
  b -= NB_T3;
  {
    int i = b * 256 + t;
    const uint4 z = make_uint4(0, 0, 0, 0);
    if (i < (MP - NND) * DH / 8) { ((uint4*)hbp)[i] = z; ((uint4*)h2bp)[i] = z; }
    if (i < NND) indeg[i] = 0;
  }
}

// ---------------- projected attention vectors: pv[v][k] = sum_c WT[h*256+c][k]*a[h][c] ----------------
// v = h*2 + (0:src,1:dst). Uses the bf16 transposed weights (coalesced over k).

__global__ void k_aproj(const u16* __restrict__ wt, const float* __restrict__ a_s,
                        const float* __restrict__ a_d, float* __restrict__ pv, int K) {
  const int v = blockIdx.x, h = v >> 1, sd = v & 1, t = threadIdx.x;
  const float* av = sd ? a_d : a_s;
  for (int k0 = t; k0 < K; k0 += 256) {
    float acc = 0.f;
    for (int c = 0; c < 256; c++)
      acc += bf2f(wt[(size_t)(h * 256 + c) * K + k0]) * av[h * 256 + c];
    pv[v * K + k0] = acc;
  }
}

// ---------------- attention logits via GEMV on the GEMM input rows ----------------
// al_s[n,h] = rows[n,:] . pv[h*2+0], al_d[n,h] = rows[n,:] . pv[h*2+1]

template <int K>
__global__ __launch_bounds__(64) void k_alv(const u16* __restrict__ rows,
                                            const float* __restrict__ pv,
                                            float* __restrict__ als,
                                            float* __restrict__ ald) {
  const int n = blockIdx.x, ln = threadIdx.x;
  constexpr int EPL = K / 64;   // elems per lane (8 or 16)
  float xr[EPL];
  const uint4* rp4 = (const uint4*)(rows + (size_t)n * K + ln * EPL);
#pragma unroll
  for (int q = 0; q < EPL / 8; q++) {
    uint4 hv = rp4[q];
    xr[q * 8 + 0] = bflo(hv.x); xr[q * 8 + 1] = bfhi(hv.x);
    xr[q * 8 + 2] = bflo(hv.y); xr[q * 8 + 3] = bfhi(hv.y);
    xr[q * 8 + 4] = bflo(hv.z); xr[q * 8 + 5] = bfhi(hv.z);
    xr[q * 8 + 6] = bflo(hv.w); xr[q * 8 + 7] = bfhi(hv.w);
  }
  float d[8];
#pragma unroll
  for (int v = 0; v < 8; v++) {
    const float* pvv = pv + v * K + ln * EPL;
    float s = 0.f;
#pragma unroll
    for (int j = 0; j < EPL; j++) s += xr[j] * pvv[j];
#pragma unroll
    for (int off = 32; off; off >>= 1) s += __shfl_xor(s, off);
    d[v] = s;
  }
  if (ln == 0) {
    als[n * 4 + 0] = d[0]; ald[n * 4 + 0] = d[1];
    als[n * 4 + 1] = d[2]; ald[n * 4 + 1] = d[3];
    als[n * 4 + 2] = d[4]; ald[n * 4 + 2] = d[5];
    als[n * 4 + 3] = d[6]; ald[n * 4 + 3] = d[7];
  }
}

// ---------------- CSR build ----------------

__global__ void k_count(const int* __restrict__ ei, int* __restrict__ indeg) {
  int e = blockIdx.x * 256 + threadIdx.x;
  if (e >= NET) return;
  int dst = (e < NED) ? ei[NED + e] : (e - NED);
  atomicAdd(&indeg[dst], 1);
}

// 3-stage multi-block scan over indeg -> rowp (exclusive, rowp[0]=0)
__global__ void k_scan1(const int* __restrict__ indeg, int* __restrict__ rowp,
                        int* __restrict__ bsum) {
  __shared__ int ws[4];
  const int b = blockIdx.x, t = threadIdx.x, wv = t >> 6, ln = t & 63;
  const int i = b * 256 + t;
  int v = (i < NND) ? indeg[i] : 0;
  int sc = v;
#pragma unroll
  for (int off = 1; off < 64; off <<= 1) {
    int xx = __shfl_up(sc, off);
    if (ln >= off) sc += xx;
  }
  if (ln == 63) ws[wv] = sc;
  __syncthreads();
  if (t == 0) {
    int a = 0;
#pragma unroll
    for (int k = 0; k < 4; k++) { int tmp = ws[k]; ws[k] = a; a += tmp; }
    bsum[b] = a;
  }
  __syncthreads();
  sc += ws[wv];
  if (i < NND) rowp[i + 1] = sc;   // block-local inclusive
}

__global__ void k_scan2(int* __restrict__ bsum) {   // 1 block, 64 threads
  int t = threadIdx.x;
  int v = (t < SCB) ? bsum[t] : 0;
  int sc = v;
#pragma unroll
  for (int off = 1; off < 64; off <<= 1) {
    int xx = __shfl_up(sc, off);
    if (t >= off) sc += xx;
  }
  if (t < SCB) bsum[t] = sc - v;   // exclusive
}

__global__ void k_scan3(int* __restrict__ rowp, const int* __restrict__ bsum,
                        int* __restrict__ cursor) {
  const int b = blockIdx.x, t = threadIdx.x;
  const int i = b * 256 + t;
  if (i < NND) { rowp[i + 1] += bsum[b]; cursor[i] = 0; }
  if (i == 0) rowp[0] = 0;
}

__global__ void k_fill(const int* __restrict__ ei, const int* __restrict__ rowp,
                       int* __restrict__ cursor, int* __restrict__ colsrc) {
  int e = blockIdx.x * 256 + threadIdx.x;
  if (e >= NET) return;
  int src, dst;
  if (e < NED) { src = ei[e]; dst = ei[NED + e]; }
  else         { src = dst = e - NED; }
  int pos = rowp[dst] + atomicAdd(&cursor[dst], 1);
  colsrc[pos] = src;
}

// ---------------- GEMM: C[M][ldc] = A[M][KD] * BT[Nt][KD]^T (+bias) ----------------
// bf16 inputs, fp32 accum. Output bf16 (OUTBF) or fp32. 128x128 tile, BK=32,
// 4 waves, 16x16x32 MFMA, global_load_lds width-16 staging, XCD-chunked swizzle.
// LDS anti-bank-conflict: 16B-slot XOR swizzle, slot ^= (row>>1)&3, applied on the
// GLOBAL source at staging (gl_lds dest must stay linear) and on the ds_read offset.

template <int KD, int GX, bool HAS_BIAS, bool GUARD, bool OUTBF>
__global__ __launch_bounds__(256) void k_gemm(const u16* __restrict__ A,
                                              const u16* __restrict__ BT,
                                              float* __restrict__ Cf,
                                              u16* __restrict__ Cb,
                                              const float* __restrict__ bias,
                                              int ldc, int mvalid) {
  __shared__ __align__(16) u16 As[128 * 32];
  __shared__ __align__(16) u16 Bs[128 * 32];
  const int tid = threadIdx.x;
  const int lane = tid & 63;
  const int w = tid >> 6;
  const int wr = w >> 1, wc = w & 1;
  const int l15 = lane & 15;
  const int kg = (lane >> 4) * 8;
  const int kgs = kg ^ (((l15 >> 1) & 3) * 8);   // swizzled read slot

  // XCD-chunked bijective swizzle (m204)
  const int nwg = GX * gridDim.y;
  const int bid = blockIdx.y * GX + blockIdx.x;
  const int q = nwg >> 3, r = nwg & 7;
  const int xcd = bid & 7, idx = bid >> 3;
  const int swz = (xcd < r ? xcd * (q + 1) : r * (q + 1) + (xcd - r) * q) + idx;
  const int mt = swz / GX, nt = swz % GX;

  const int flat0 = tid * 8;
  const int row0 = tid >> 2;                         // rows 0..63 (chunk 0)
  const int kk0 = (((tid & 3) ^ ((tid >> 3) & 3)) * 8);  // swizzled source slot
  const int row1 = 64 + row0;                        // chunk 1; same (row>>1)&3

  const u16* Ab = A + (size_t)(mt * 128) * KD;
  const u16* Bb = BT + (size_t)(nt * 128) * KD;
  const u16* ga0 = Ab + row0 * KD + kk0;
  const u16* ga1 = Ab + row1 * KD + kk0;
  const u16* gb0 = Bb + row0 * KD + kk0;
  const u16* gb1 = Bb + row1 * KD + kk0;
  u16* lA0 = As + flat0;
  u16* lA1 = As + 2048 + flat0;
  u16* lB0 = Bs + flat0;
  u16* lB1 = Bs + 2048 + flat0;

  f32x4_t acc[4][4];
#pragma unroll
  for (int i = 0; i < 4; i++)
#pragma unroll
    for (int j = 0; j < 4; j++)
#pragma unroll
      for (int q2 = 0; q2 < 4; q2++) acc[i][j][q2] = 0.f;

  for (int kt = 0; kt < KD; kt += 32) {
    __syncthreads();
    gl_lds16(ga0 + kt, lA0);
    gl_lds16(ga1 + kt, lA1);
    gl_lds16(gb0 + kt, lB0);
    gl_lds16(gb1 + kt, lB1);
    __syncthreads();
    short8_t af[4], bfr[4];
#pragma unroll
    for (int i = 0; i < 4; i++)
      af[i] = *(const short8_t*)(As + (wr * 64 + i * 16 + l15) * 32 + kgs);
#pragma unroll
    for (int i = 0; i < 4; i++)
      bfr[i] = *(const short8_t*)(Bs + (wc * 64 + i * 16 + l15) * 32 + kgs);
#pragma unroll
    for (int i = 0; i < 4; i++)
#pragma unroll
      for (int j = 0; j < 4; j++)
        acc[i][j] = __builtin_amdgcn_mfma_f32_16x16x32_bf16(af[i], bfr[j], acc[i][j], 0, 0, 0);
  }

  const int rbase = mt * 128 + wr * 64 + (lane >> 4) * 4;
  const int cbase = nt * 128 + wc * 64 + l15;
#pragma unroll
  for (int i = 0; i < 4; i++) {
#pragma unroll
    for (int j = 0; j < 4; j++) {
#pragma unroll
      for (int q2 = 0; q2 < 4; q2++) {
        int rr = rbase + i * 16 + q2;
        int cc = cbase + j * 16;
        if (!GUARD || rr < mvalid) {
          float v = acc[i][j][q2];
          if (HAS_BIAS) v += bias[cc];
          if (OUTBF) Cb[(size_t)rr * ldc + cc] = f2bf(v);
          else       Cf[(size_t)rr * ldc + cc] = v;
        }
      }
    }
  }
}

// ---------------- fused segment-softmax + gather: one wave per (dst, ch-half) ----------------
// pass 1: per-head max, strided per 32-lane HALF so both heads cover all edges.
// pass 2: accumulate sum(w*h), sum(w) with w=exp inline; max cancels in alpha.

__global__ __launch_bounds__(64) void k_agg2(const u16* __restrict__ hprojb,
                                             const float* __restrict__ als,
                                             const float* __restrict__ ald,
                                             const int* __restrict__ rowp,
                                             const int* __restrict__ colsrc,
                                             const float* __restrict__ bias,
                                             u16* __restrict__ outb) {
  const int n = blockIdx.x, half = blockIdx.y, ln = threadIdx.x;
  const int beg = rowp[n], end = rowp[n + 1];
  const int hsel = 2 * half + (ln >> 5);          // head for this lane's 8 channels
  const float adv = ald[n * 4 + hsel];

  // pass 1: max of leaky_relu(al_s[src]+al_d[n]) for own head, per 32-lane half
  float m = -1e30f;
  for (int e = beg + (ln & 31); e < end; e += 32)
    m = fmaxf(m, lrelu(als[colsrc[e] * 4 + hsel] + adv));
#pragma unroll
  for (int off = 16; off; off >>= 1) m = fmaxf(m, __shfl_xor(m, off));

  // pass 2: gather with inline softmax weight
  const u16* hbase = hprojb + half * 512 + ln * 8;
  float a0 = 0.f, a1 = 0.f, a2 = 0.f, a3 = 0.f;
  float a4 = 0.f, a5 = 0.f, a6 = 0.f, a7 = 0.f;
  float ds = 0.f;
  int e = beg;
  for (; e + 1 < end; e += 2) {
    int s0 = colsrc[e], s1 = colsrc[e + 1];
    float w0 = __expf(lrelu(als[s0 * 4 + hsel] + adv) - m);
    float w1 = __expf(lrelu(als[s1 * 4 + hsel] + adv) - m);
    uint4 h0 = *(const uint4*)(hbase + (size_t)s0 * DH);
    uint4 h1 = *(const uint4*)(hbase + (size_t)s1 * DH);
    a0 += bflo(h0.x) * w0; a1 += bfhi(h0.x) * w0;
    a2 += bflo(h0.y) * w0; a3 += bfhi(h0.y) * w0;
    a4 += bflo(h0.z) * w0; a5 += bfhi(h0.z) * w0;
    a6 += bflo(h0.w) * w0; a7 += bfhi(h0.w) * w0;
    a0 += bflo(h1.x) * w1; a1 += bfhi(h1.x) * w1;
    a2 += bflo(h1.y) * w1; a3 += bfhi(h1.y) * w1;
    a4 += bflo(h1.z) * w1; a5 += bfhi(h1.z) * w1;
    a6 += bflo(h1.w) * w1; a7 += bfhi(h1.w) * w1;
    ds += w0 + w1;
  }
  if (e < end) {
    int s0 = colsrc[e];
    float w0 = __expf(lrelu(als[s0 * 4 + hsel] + adv) - m);
    uint4 h0 = *(const uint4*)(hbase + (size_t)s0 * DH);
    a0 += bflo(h0.x) * w0; a1 += bfhi(h0.x) * w0;
    a2 += bflo(h0.y) * w0; a3 += bfhi(h0.y) * w0;
    a4 += bflo(h0.z) * w0; a5 += bfhi(h0.z) * w0;
    a6 += bflo(h0.w) * w0; a7 += bfhi(h0.w) * w0;
    ds += w0;
  }

  const float inv = 1.f / ds;
  const float4 bv0 = *(const float4*)(bias + half * 512 + ln * 8);
  const float4 bv1 = *(const float4*)(bias + half * 512 + ln * 8 + 4);
  float o0 = fmaxf(a0 * inv + bv0.x, 0.f), o1 = fmaxf(a1 * inv + bv0.y, 0.f);
  float o2 = fmaxf(a2 * inv + bv0.z, 0.f), o3 = fmaxf(a3 * inv + bv0.w, 0.f);
  float o4 = fmaxf(a4 * inv + bv1.x, 0.f), o5 = fmaxf(a5 * inv + bv1.y, 0.f);
  float o6 = fmaxf(a6 * inv + bv1.z, 0.f), o7 = fmaxf(a7 * inv + bv1.w, 0.f);
  uint4 ob;
  ob.x = (unsigned)f2bf(o0) | ((unsigned)f2bf(o1) << 16);
  ob.y = (unsigned)f2bf(o2) | ((unsigned)f2bf(o3) << 16);
  ob.z = (unsigned)f2bf(o4) | ((unsigned)f2bf(o5) << 16);
  ob.w = (unsigned)f2bf(o6) | ((unsigned)f2bf(o7) << 16);
  *(uint4*)(outb + (size_t)n * DH + half * 512 + ln * 8) = ob;
}

// ---------------- launcher ----------------

extern "C" void kernel_launch(void* const* d_in, const int* in_sizes, int n_in,
                              void* d_out, int out_size, void* d_ws, size_t ws_size,
                              hipStream_t stream) {
  const float* x   = (const float*)d_in[0];
  const int*   ei  = (const int*)d_in[1];
  const float* W1  = (const float*)d_in[2];
  const float* as1 = (const float*)d_in[3];
  const float* ad1 = (const float*)d_in[4];
  const float* b1  = (const float*)d_in[5];
  const float* W2  = (const float*)d_in[6];
  const float* as2 = (const float*)d_in[7];
  const float* ad2 = (const float*)d_in[8];
  const float* b2  = (const float*)d_in[9];
  const float* Wfc = (const float*)d_in[10];
  const float* bfc = (const float*)d_in[11];
  float* out = (float*)d_out;
  (void)in_sizes; (void)n_in; (void)out_size; (void)ws_size;

  // workspace carve
  char* p = (char*)d_ws;
  auto carve = [&](size_t bytes) -> char* {
    char* r = p; p += (bytes + 255) & ~(size_t)255; return r;
  };
  u16*   xb     = (u16*)  carve((size_t)MP * DIN * 2);
  u16*   w1t    = (u16*)  carve((size_t)DH * DIN * 2);
  u16*   w2t    = (u16*)  carve((size_t)DH * DH * 2);
  u16*   wft    = (u16*)  carve((size_t)DOUT * DH * 2);
  u16*   hprojb = (u16*)  carve((size_t)MP * DH * 2);
  u16*   hb     = (u16*)  carve((size_t)MP * DH * 2);
  u16*   h2b    = (u16*)  carve((size_t)MP * DH * 2);
  float* als1   = (float*)carve((size_t)NND * 4 * 4);
  float* ald1   = (float*)carve((size_t)NND * 4 * 4);
  float* als2   = (float*)carve((size_t)NND * 4 * 4);
  float* ald2   = (float*)carve((size_t)NND * 4 * 4);
  float* pv1    = (float*)carve((size_t)8 * DIN * 4);
  float* pv2    = (float*)carve((size_t)8 * DH * 4);
  int*   indeg  = (int*)  carve((size_t)NND * 4);
  int*   rowp   = (int*)  carve((size_t)(NND + 1) * 4);
  int*   cursor = (int*)  carve((size_t)NND * 4);
  int*   colsrc = (int*)  carve((size_t)NET * 4);
  int*   bsum   = (int*)  carve((size_t)SCB * 4);

  // prep (merged) + projected attention vectors + CSR
  k_prep<<<NB_PREP, 256, 0, stream>>>(x, xb, W1, w1t, W2, w2t, Wfc, wft,
      indeg, hb + (size_t)NND * DH, h2b + (size_t)NND * DH);
  k_aproj<<<8, 256, 0, stream>>>(w1t, as1, ad1, pv1, DIN);
  k_aproj<<<8, 256, 0, stream>>>(w2t, as2, ad2, pv2, DH);
  k_count<<<(NET + 255) / 256, 256, 0, stream>>>(ei, indeg);
  k_scan1<<<SCB, 256, 0, stream>>>(indeg, rowp, bsum);
  k_scan2<<<1, 64, 0, stream>>>(bsum);
  k_scan3<<<SCB, 256, 0, stream>>>(rowp, bsum, cursor);
  k_fill<<<(NET + 255) / 256, 256, 0, stream>>>(ei, rowp, cursor, colsrc);

  // layer 1: logits from xb via GEMV, GEMM, fused softmax-gather
  k_alv<DIN><<<NND, 64, 0, stream>>>(xb, pv1, als1, ald1);
  k_gemm<DIN, 8, false, false, true><<<dim3(DH / 128, MP / 128), 256, 0, stream>>>(
      xb, w1t, nullptr, hprojb, nullptr, DH, MP);
  k_agg2<<<dim3(NND, 2), 64, 0, stream>>>(hprojb, als1, ald1, rowp, colsrc, b1, hb);

  // layer 2
  k_alv<DH><<<NND, 64, 0, stream>>>(hb, pv2, als2, ald2);
  k_gemm<DH, 8, false, false, true><<<dim3(DH / 128, MP / 128), 256, 0, stream>>>(
      hb, w2t, nullptr, hprojb, nullptr, DH, MP);
  k_agg2<<<dim3(NND, 2), 64, 0, stream>>>(hprojb, als2, ald2, rowp, colsrc, b2, h2b);

  // FC
  k_gemm<DH, 4, true, true, false><<<dim3(DOUT / 128, MP / 128), 256, 0, stream>>>(
      h2b, wft, out, nullptr, bfc, DOUT, NND);
}

// Round 8
// 232.378 us; speedup vs baseline: 1.4403x; 1.4403x over previous
//
#include <hip/hip_runtime.h>

// Problem constants
#define NND 10000      // nodes
#define NED 160000     // edges (before self loops)
#define NET 170000     // edges incl self loops
#define MP  10112      // node rows padded to multiple of 128 (79*128)
#define DH  1024       // H*C hidden width
#define DIN 512
#define DOUT 512
#define SCB 40         // scan blocks: ceil(NND/256)

// prep kernel block ranges
#define NB_CONV 5056   // MP*DIN/4/256
#define NB_T1   512    // (DH/32)*(DIN/32)
#define NB_T2   1024   // (DH/32)*(DH/32)
#define NB_T3   512    // (DOUT/32)*(DH/32)
#define NB_Z    80
#define NB_PREP (NB_CONV + NB_T1 + NB_T2 + NB_T3 + NB_Z)

typedef unsigned short u16;
typedef __attribute__((ext_vector_type(8))) short short8_t;
typedef __attribute__((ext_vector_type(4))) float f32x4_t;

__device__ __forceinline__ u16 f2bf(float f) {
  unsigned u = __float_as_uint(f);
  return (u16)((u + 0x7fffu + ((u >> 16) & 1u)) >> 16);
}
__device__ __forceinline__ float bf2f(u16 b) {
  return __uint_as_float(((unsigned)b) << 16);
}
__device__ __forceinline__ float bflo(unsigned u) { return __uint_as_float(u << 16); }
__device__ __forceinline__ float bfhi(unsigned u) { return __uint_as_float(u & 0xffff0000u); }
__device__ __forceinline__ float lrelu(float v) { return v > 0.f ? v : 0.2f * v; }

// async global->LDS, 16B per lane. LDS dest must be linear (uniform base + lane*16).
__device__ __forceinline__ void gl_lds16(const void* g, void* l) {
  __builtin_amdgcn_global_load_lds(
      (const __attribute__((address_space(1))) unsigned int*)g,
      (__attribute__((address_space(3))) unsigned int*)l, 16, 0, 0);
}

// ---------------- merged prep: x->bf16, 3 weight transposes, zeroing ----------------

__device__ __forceinline__ void dev_transpose(const float* __restrict__ W,
                                              u16* __restrict__ WT,
                                              int K, int Nt, int bx, int by, int t) {
  __shared__ float s[32][33];
  const int kt = by * 32, nt = bx * 32;
  const int tx = t & 31, ty = t >> 5;   // (32,8)
#pragma unroll
  for (int i = 0; i < 32; i += 8)
    s[ty + i][tx] = W[(size_t)(kt + ty + i) * Nt + nt + tx];
  __syncthreads();
#pragma unroll
  for (int i = 0; i < 32; i += 8)
    WT[(size_t)(nt + ty + i) * K + kt + tx] = f2bf(s[tx][ty + i]);
}

__global__ void k_prep(const float* __restrict__ x, u16* __restrict__ xb,
                       const float* __restrict__ W1, u16* __restrict__ w1t,
                       const float* __restrict__ W2, u16* __restrict__ w2t,
                       const float* __restrict__ Wfc, u16* __restrict__ wft,
                       int* __restrict__ indeg,
                       u16* __restrict__ hbp, u16* __restrict__ h2bp) {
  int b = blockIdx.x, t = threadIdx.x;
  if (b < NB_CONV) {
    int i = b * 256 + t;
    float4 v = make_float4(0.f, 0.f, 0.f, 0.f);
    if (i < NND * DIN / 4) v = ((const float4*)x)[i];
    ushort4 o;
    o.x = f2bf(v.x); o.y = f2bf(v.y); o.z = f2bf(v.z); o.w = f2bf(v.w);
    ((ushort4*)xb)[i] = o;
    return;
  }
  b -= NB_CONV;
  if (b < NB_T1) { dev_transpose(W1, w1t, DIN, DH, b & 31, b >> 5, t); return; }
  b -= NB_T1;
  if (b < NB_T2) { dev_transpose(W2, w2t, DH, DH, b & 31, b >> 5, t); return; }
  b -= NB_T2;
  if (b < NB_T3) { dev_transpose(Wfc, wft, DH, DOUT, b & 15, b >> 4, t); return; }
  b -= NB_T3;
  {
    int i = b * 256 + t;
    const uint4 z = make_uint4(0, 0, 0, 0);
    if (i < (MP - NND) * DH / 8) { ((uint4*)hbp)[i] = z; ((uint4*)h2bp)[i] = z; }
    if (i < NND) indeg[i] = 0;
  }
}

// ---------------- projected attention vectors ----------------
// pv[(h*2+sd)*K + k] = sum_c W[k][h*256+c] * a_{sd}[h][c].
// One wave per (k, h): 64 lanes x float4 = 256 channels; W row is contiguous fp32.

__global__ __launch_bounds__(64) void k_aproj(const float* __restrict__ W,
                                              const float* __restrict__ a_s,
                                              const float* __restrict__ a_d,
                                              float* __restrict__ pv, int K) {
  const int k = blockIdx.x, h = blockIdx.y, ln = threadIdx.x;
  const float4 wv  = *(const float4*)(W + (size_t)k * DH + h * 256 + ln * 4);
  const float4 asv = *(const float4*)(a_s + h * 256 + ln * 4);
  const float4 adv = *(const float4*)(a_d + h * 256 + ln * 4);
  float ps = wv.x * asv.x + wv.y * asv.y + wv.z * asv.z + wv.w * asv.w;
  float pd = wv.x * adv.x + wv.y * adv.y + wv.z * adv.z + wv.w * adv.w;
#pragma unroll
  for (int off = 32; off; off >>= 1) {
    ps += __shfl_xor(ps, off);
    pd += __shfl_xor(pd, off);
  }
  if (ln == 0) {
    pv[(h * 2 + 0) * K + k] = ps;
    pv[(h * 2 + 1) * K + k] = pd;
  }
}

// ---------------- attention logits via GEMV on the GEMM input rows ----------------
// al_s[n,h] = rows[n,:] . pv[h*2+0], al_d[n,h] = rows[n,:] . pv[h*2+1]

template <int K>
__global__ __launch_bounds__(64) void k_alv(const u16* __restrict__ rows,
                                            const float* __restrict__ pv,
                                            float* __restrict__ als,
                                            float* __restrict__ ald) {
  const int n = blockIdx.x, ln = threadIdx.x;
  constexpr int EPL = K / 64;   // elems per lane (8 or 16)
  float xr[EPL];
  const uint4* rp4 = (const uint4*)(rows + (size_t)n * K + ln * EPL);
#pragma unroll
  for (int q = 0; q < EPL / 8; q++) {
    uint4 hv = rp4[q];
    xr[q * 8 + 0] = bflo(hv.x); xr[q * 8 + 1] = bfhi(hv.x);
    xr[q * 8 + 2] = bflo(hv.y); xr[q * 8 + 3] = bfhi(hv.y);
    xr[q * 8 + 4] = bflo(hv.z); xr[q * 8 + 5] = bfhi(hv.z);
    xr[q * 8 + 6] = bflo(hv.w); xr[q * 8 + 7] = bfhi(hv.w);
  }
  float d[8];
#pragma unroll
  for (int v = 0; v < 8; v++) {
    const float* pvv = pv + v * K + ln * EPL;
    float s = 0.f;
#pragma unroll
    for (int j = 0; j < EPL; j++) s += xr[j] * pvv[j];
#pragma unroll
    for (int off = 32; off; off >>= 1) s += __shfl_xor(s, off);
    d[v] = s;
  }
  if (ln == 0) {
    als[n * 4 + 0] = d[0]; ald[n * 4 + 0] = d[1];
    als[n * 4 + 1] = d[2]; ald[n * 4 + 1] = d[3];
    als[n * 4 + 2] = d[4]; ald[n * 4 + 2] = d[5];
    als[n * 4 + 3] = d[6]; ald[n * 4 + 3] = d[7];
  }
}

// ---------------- CSR build ----------------

__global__ void k_count(const int* __restrict__ ei, int* __restrict__ indeg) {
  int e = blockIdx.x * 256 + threadIdx.x;
  if (e >= NET) return;
  int dst = (e < NED) ? ei[NED + e] : (e - NED);
  atomicAdd(&indeg[dst], 1);
}

// 3-stage multi-block scan over indeg -> rowp (exclusive, rowp[0]=0)
__global__ void k_scan1(const int* __restrict__ indeg, int* __restrict__ rowp,
                        int* __restrict__ bsum) {
  __shared__ int ws[4];
  const int b = blockIdx.x, t = threadIdx.x, wv = t >> 6, ln = t & 63;
  const int i = b * 256 + t;
  int v = (i < NND) ? indeg[i] : 0;
  int sc = v;
#pragma unroll
  for (int off = 1; off < 64; off <<= 1) {
    int xx = __shfl_up(sc, off);
    if (ln >= off) sc += xx;
  }
  if (ln == 63) ws[wv] = sc;
  __syncthreads();
  if (t == 0) {
    int a = 0;
#pragma unroll
    for (int k = 0; k < 4; k++) { int tmp = ws[k]; ws[k] = a; a += tmp; }
    bsum[b] = a;
  }
  __syncthreads();
  sc += ws[wv];
  if (i < NND) rowp[i + 1] = sc;   // block-local inclusive
}

__global__ void k_scan2(int* __restrict__ bsum) {   // 1 block, 64 threads
  int t = threadIdx.x;
  int v = (t < SCB) ? bsum[t] : 0;
  int sc = v;
#pragma unroll
  for (int off = 1; off < 64; off <<= 1) {
    int xx = __shfl_up(sc, off);
    if (t >= off) sc += xx;
  }
  if (t < SCB) bsum[t] = sc - v;   // exclusive
}

__global__ void k_scan3(int* __restrict__ rowp, const int* __restrict__ bsum,
                        int* __restrict__ cursor) {
  const int b = blockIdx.x, t = threadIdx.x;
  const int i = b * 256 + t;
  if (i < NND) { rowp[i + 1] += bsum[b]; cursor[i] = 0; }
  if (i == 0) rowp[0] = 0;
}

__global__ void k_fill(const int* __restrict__ ei, const int* __restrict__ rowp,
                       int* __restrict__ cursor, int* __restrict__ colsrc) {
  int e = blockIdx.x * 256 + threadIdx.x;
  if (e >= NET) return;
  int src, dst;
  if (e < NED) { src = ei[e]; dst = ei[NED + e]; }
  else         { src = dst = e - NED; }
  int pos = rowp[dst] + atomicAdd(&cursor[dst], 1);
  colsrc[pos] = src;
}

// ---------------- GEMM: C[M][ldc] = A[M][KD] * BT[Nt][KD]^T (+bias) ----------------
// bf16 inputs, fp32 accum. Output bf16 (OUTBF) or fp32. 128x128 tile, BK=32,
// 4 waves, 16x16x32 MFMA, global_load_lds width-16 staging, XCD-chunked swizzle.
// LDS anti-bank-conflict: 16B-slot XOR swizzle, slot ^= (row>>1)&3, applied on the
// GLOBAL source at staging (gl_lds dest must stay linear) and on the ds_read offset.

template <int KD, int GX, bool HAS_BIAS, bool GUARD, bool OUTBF>
__global__ __launch_bounds__(256) void k_gemm(const u16* __restrict__ A,
                                              const u16* __restrict__ BT,
                                              float* __restrict__ Cf,
                                              u16* __restrict__ Cb,
                                              const float* __restrict__ bias,
                                              int ldc, int mvalid) {
  __shared__ __align__(16) u16 As[128 * 32];
  __shared__ __align__(16) u16 Bs[128 * 32];
  const int tid = threadIdx.x;
  const int lane = tid & 63;
  const int w = tid >> 6;
  const int wr = w >> 1, wc = w & 1;
  const int l15 = lane & 15;
  const int kg = (lane >> 4) * 8;
  const int kgs = kg ^ (((l15 >> 1) & 3) * 8);   // swizzled read slot

  // XCD-chunked bijective swizzle (m204)
  const int nwg = GX * gridDim.y;
  const int bid = blockIdx.y * GX + blockIdx.x;
  const int q = nwg >> 3, r = nwg & 7;
  const int xcd = bid & 7, idx = bid >> 3;
  const int swz = (xcd < r ? xcd * (q + 1) : r * (q + 1) + (xcd - r) * q) + idx;
  const int mt = swz / GX, nt = swz % GX;

  const int flat0 = tid * 8;
  const int row0 = tid >> 2;                         // rows 0..63 (chunk 0)
  const int kk0 = (((tid & 3) ^ ((tid >> 3) & 3)) * 8);  // swizzled source slot
  const int row1 = 64 + row0;                        // chunk 1; same (row>>1)&3

  const u16* Ab = A + (size_t)(mt * 128) * KD;
  const u16* Bb = BT + (size_t)(nt * 128) * KD;
  const u16* ga0 = Ab + row0 * KD + kk0;
  const u16* ga1 = Ab + row1 * KD + kk0;
  const u16* gb0 = Bb + row0 * KD + kk0;
  const u16* gb1 = Bb + row1 * KD + kk0;
  u16* lA0 = As + flat0;
  u16* lA1 = As + 2048 + flat0;
  u16* lB0 = Bs + flat0;
  u16* lB1 = Bs + 2048 + flat0;

  f32x4_t acc[4][4];
#pragma unroll
  for (int i = 0; i < 4; i++)
#pragma unroll
    for (int j = 0; j < 4; j++)
#pragma unroll
      for (int q2 = 0; q2 < 4; q2++) acc[i][j][q2] = 0.f;

  for (int kt = 0; kt < KD; kt += 32) {
    __syncthreads();
    gl_lds16(ga0 + kt, lA0);
    gl_lds16(ga1 + kt, lA1);
    gl_lds16(gb0 + kt, lB0);
    gl_lds16(gb1 + kt, lB1);
    __syncthreads();
    short8_t af[4], bfr[4];
#pragma unroll
    for (int i = 0; i < 4; i++)
      af[i] = *(const short8_t*)(As + (wr * 64 + i * 16 + l15) * 32 + kgs);
#pragma unroll
    for (int i = 0; i < 4; i++)
      bfr[i] = *(const short8_t*)(Bs + (wc * 64 + i * 16 + l15) * 32 + kgs);
#pragma unroll
    for (int i = 0; i < 4; i++)
#pragma unroll
      for (int j = 0; j < 4; j++)
        acc[i][j] = __builtin_amdgcn_mfma_f32_16x16x32_bf16(af[i], bfr[j], acc[i][j], 0, 0, 0);
  }

  const int rbase = mt * 128 + wr * 64 + (lane >> 4) * 4;
  const int cbase = nt * 128 + wc * 64 + l15;
#pragma unroll
  for (int i = 0; i < 4; i++) {
#pragma unroll
    for (int j = 0; j < 4; j++) {
#pragma unroll
      for (int q2 = 0; q2 < 4; q2++) {
        int rr = rbase + i * 16 + q2;
        int cc = cbase + j * 16;
        if (!GUARD || rr < mvalid) {
          float v = acc[i][j][q2];
          if (HAS_BIAS) v += bias[cc];
          if (OUTBF) Cb[(size_t)rr * ldc + cc] = f2bf(v);
          else       Cf[(size_t)rr * ldc + cc] = v;
        }
      }
    }
  }
}

// ---------------- fused segment-softmax + gather: one wave per (dst, ch-half) ----------------
// pass 1: per-head max, strided per 32-lane HALF so both heads cover all edges.
// pass 2: accumulate sum(w*h), sum(w) with w=exp inline; max cancels in alpha.

__global__ __launch_bounds__(64) void k_agg2(const u16* __restrict__ hprojb,
                                             const float* __restrict__ als,
                                             const float* __restrict__ ald,
                                             const int* __restrict__ rowp,
                                             const int* __restrict__ colsrc,
                                             const float* __restrict__ bias,
                                             u16* __restrict__ outb) {
  const int n = blockIdx.x, half = blockIdx.y, ln = threadIdx.x;
  const int beg = rowp[n], end = rowp[n + 1];
  const int hsel = 2 * half + (ln >> 5);          // head for this lane's 8 channels
  const float adv = ald[n * 4 + hsel];

  // pass 1: max of leaky_relu(al_s[src]+al_d[n]) for own head, per 32-lane half
  float m = -1e30f;
  for (int e = beg + (ln & 31); e < end; e += 32)
    m = fmaxf(m, lrelu(als[colsrc[e] * 4 + hsel] + adv));
#pragma unroll
  for (int off = 16; off; off >>= 1) m = fmaxf(m, __shfl_xor(m, off));

  // pass 2: gather with inline softmax weight
  const u16* hbase = hprojb + half * 512 + ln * 8;
  float a0 = 0.f, a1 = 0.f, a2 = 0.f, a3 = 0.f;
  float a4 = 0.f, a5 = 0.f, a6 = 0.f, a7 = 0.f;
  float ds = 0.f;
  int e = beg;
  for (; e + 1 < end; e += 2) {
    int s0 = colsrc[e], s1 = colsrc[e + 1];
    float w0 = __expf(lrelu(als[s0 * 4 + hsel] + adv) - m);
    float w1 = __expf(lrelu(als[s1 * 4 + hsel] + adv) - m);
    uint4 h0 = *(const uint4*)(hbase + (size_t)s0 * DH);
    uint4 h1 = *(const uint4*)(hbase + (size_t)s1 * DH);
    a0 += bflo(h0.x) * w0; a1 += bfhi(h0.x) * w0;
    a2 += bflo(h0.y) * w0; a3 += bfhi(h0.y) * w0;
    a4 += bflo(h0.z) * w0; a5 += bfhi(h0.z) * w0;
    a6 += bflo(h0.w) * w0; a7 += bfhi(h0.w) * w0;
    a0 += bflo(h1.x) * w1; a1 += bfhi(h1.x) * w1;
    a2 += bflo(h1.y) * w1; a3 += bfhi(h1.y) * w1;
    a4 += bflo(h1.z) * w1; a5 += bfhi(h1.z) * w1;
    a6 += bflo(h1.w) * w1; a7 += bfhi(h1.w) * w1;
    ds += w0 + w1;
  }
  if (e < end) {
    int s0 = colsrc[e];
    float w0 = __expf(lrelu(als[s0 * 4 + hsel] + adv) - m);
    uint4 h0 = *(const uint4*)(hbase + (size_t)s0 * DH);
    a0 += bflo(h0.x) * w0; a1 += bfhi(h0.x) * w0;
    a2 += bflo(h0.y) * w0; a3 += bfhi(h0.y) * w0;
    a4 += bflo(h0.z) * w0; a5 += bfhi(h0.z) * w0;
    a6 += bflo(h0.w) * w0; a7 += bfhi(h0.w) * w0;
    ds += w0;
  }

  const float inv = 1.f / ds;
  const float4 bv0 = *(const float4*)(bias + half * 512 + ln * 8);
  const float4 bv1 = *(const float4*)(bias + half * 512 + ln * 8 + 4);
  float o0 = fmaxf(a0 * inv + bv0.x, 0.f), o1 = fmaxf(a1 * inv + bv0.y, 0.f);
  float o2 = fmaxf(a2 * inv + bv0.z, 0.f), o3 = fmaxf(a3 * inv + bv0.w, 0.f);
  float o4 = fmaxf(a4 * inv + bv1.x, 0.f), o5 = fmaxf(a5 * inv + bv1.y, 0.f);
  float o6 = fmaxf(a6 * inv + bv1.z, 0.f), o7 = fmaxf(a7 * inv + bv1.w, 0.f);
  uint4 ob;
  ob.x = (unsigned)f2bf(o0) | ((unsigned)f2bf(o1) << 16);
  ob.y = (unsigned)f2bf(o2) | ((unsigned)f2bf(o3) << 16);
  ob.z = (unsigned)f2bf(o4) | ((unsigned)f2bf(o5) << 16);
  ob.w = (unsigned)f2bf(o6) | ((unsigned)f2bf(o7) << 16);
  *(uint4*)(outb + (size_t)n * DH + half * 512 + ln * 8) = ob;
}

// ---------------- launcher ----------------

extern "C" void kernel_launch(void* const* d_in, const int* in_sizes, int n_in,
                              void* d_out, int out_size, void* d_ws, size_t ws_size,
                              hipStream_t stream) {
  const float* x   = (const float*)d_in[0];
  const int*   ei  = (const int*)d_in[1];
  const float* W1  = (const float*)d_in[2];
  const float* as1 = (const float*)d_in[3];
  const float* ad1 = (const float*)d_in[4];
  const float* b1  = (const float*)d_in[5];
  const float* W2  = (const float*)d_in[6];
  const float* as2 = (const float*)d_in[7];
  const float* ad2 = (const float*)d_in[8];
  const float* b2  = (const float*)d_in[9];
  const float* Wfc = (const float*)d_in[10];
  const float* bfc = (const float*)d_in[11];
  float* out = (float*)d_out;
  (void)in_sizes; (void)n_in; (void)out_size; (void)ws_size;

  // workspace carve
  char* p = (char*)d_ws;
  auto carve = [&](size_t bytes) -> char* {
    char* r = p; p += (bytes + 255) & ~(size_t)255; return r;
  };
  u16*   xb     = (u16*)  carve((size_t)MP * DIN * 2);
  u16*   w1t    = (u16*)  carve((size_t)DH * DIN * 2);
  u16*   w2t    = (u16*)  carve((size_t)DH * DH * 2);
  u16*   wft    = (u16*)  carve((size_t)DOUT * DH * 2);
  u16*   hprojb = (u16*)  carve((size_t)MP * DH * 2);
  u16*   hb     = (u16*)  carve((size_t)MP * DH * 2);
  u16*   h2b    = (u16*)  carve((size_t)MP * DH * 2);
  float* als1   = (float*)carve((size_t)NND * 4 * 4);
  float* ald1   = (float*)carve((size_t)NND * 4 * 4);
  float* als2   = (float*)carve((size_t)NND * 4 * 4);
  float* ald2   = (float*)carve((size_t)NND * 4 * 4);
  float* pv1    = (float*)carve((size_t)8 * DIN * 4);
  float* pv2    = (float*)carve((size_t)8 * DH * 4);
  int*   indeg  = (int*)  carve((size_t)NND * 4);
  int*   rowp   = (int*)  carve((size_t)(NND + 1) * 4);
  int*   cursor = (int*)  carve((size_t)NND * 4);
  int*   colsrc = (int*)  carve((size_t)NET * 4);
  int*   bsum   = (int*)  carve((size_t)SCB * 4);

  // prep (merged) + projected attention vectors + CSR
  k_prep<<<NB_PREP, 256, 0, stream>>>(x, xb, W1, w1t, W2, w2t, Wfc, wft,
      indeg, hb + (size_t)NND * DH, h2b + (size_t)NND * DH);
  k_aproj<<<dim3(DIN, 4), 64, 0, stream>>>(W1, as1, ad1, pv1, DIN);
  k_aproj<<<dim3(DH, 4), 64, 0, stream>>>(W2, as2, ad2, pv2, DH);
  k_count<<<(NET + 255) / 256, 256, 0, stream>>>(ei, indeg);
  k_scan1<<<SCB, 256, 0, stream>>>(indeg, rowp, bsum);
  k_scan2<<<1, 64, 0, stream>>>(bsum);
  k_scan3<<<SCB, 256, 0, stream>>>(rowp, bsum, cursor);
  k_fill<<<(NET + 255) / 256, 256, 0, stream>>>(ei, rowp, cursor, colsrc);

  // layer 1: logits from xb via GEMV, GEMM, fused softmax-gather
  k_alv<DIN><<<NND, 64, 0, stream>>>(xb, pv1, als1, ald1);
  k_gemm<DIN, 8, false, false, true><<<dim3(DH / 128, MP / 128), 256, 0, stream>>>(
      xb, w1t, nullptr, hprojb, nullptr, DH, MP);
  k_agg2<<<dim3(NND, 2), 64, 0, stream>>>(hprojb, als1, ald1, rowp, colsrc, b1, hb);

  // layer 2
  k_alv<DH><<<NND, 64, 0, stream>>>(hb, pv2, als2, ald2);
  k_gemm<DH, 8, false, false, true><<<dim3(DH / 128, MP / 128), 256, 0, stream>>>(
      hb, w2t, nullptr, hprojb, nullptr, DH, MP);
  k_agg2<<<dim3(NND, 2), 64, 0, stream>>>(hprojb, als2, ald2, rowp, colsrc, b2, h2b);

  // FC
  k_gemm<DH, 4, true, true, false><<<dim3(DOUT / 128, MP / 128), 256, 0, stream>>>(
      h2b, wft, out, nullptr, bfc, DOUT, NND);
}

// Round 9
// 227.158 us; speedup vs baseline: 1.4734x; 1.0230x over previous
//
#include <hip/hip_runtime.h>

// Problem constants
#define NND 10000      // nodes
#define NED 160000     // edges (before self loops)
#define NET 170000     // edges incl self loops
#define MP  10112      // node rows padded to multiple of 128 (79*128)
#define DH  1024       // H*C hidden width
#define DIN 512
#define DOUT 512
#define SCB 40         // scan blocks: ceil(NND/256)

// prep kernel block ranges
#define NB_CONV 5056   // MP*DIN/4/256
#define NB_T1   512    // (DH/32)*(DIN/32)
#define NB_T2   1024   // (DH/32)*(DH/32)
#define NB_T3   512    // (DOUT/32)*(DH/32)
#define NB_Z    80
#define NB_AP1  512    // DIN*4/4 pairs-per-block
#define NB_AP2  1024   // DH*4/4
#define NB_PREP (NB_CONV + NB_T1 + NB_T2 + NB_T3 + NB_Z + NB_AP1 + NB_AP2)

// count+alv1 merged kernel
#define NB_CNT  665    // ceil(NET/256)
#define NB_ALV1 2500   // NND/4 (4 waves per block, 1 node per wave)

typedef unsigned short u16;
typedef __attribute__((ext_vector_type(8))) short short8_t;
typedef __attribute__((ext_vector_type(4))) float f32x4_t;

__device__ __forceinline__ u16 f2bf(float f) {
  unsigned u = __float_as_uint(f);
  return (u16)((u + 0x7fffu + ((u >> 16) & 1u)) >> 16);
}
__device__ __forceinline__ float bf2f(u16 b) {
  return __uint_as_float(((unsigned)b) << 16);
}
__device__ __forceinline__ float bflo(unsigned u) { return __uint_as_float(u << 16); }
__device__ __forceinline__ float bfhi(unsigned u) { return __uint_as_float(u & 0xffff0000u); }
__device__ __forceinline__ float lrelu(float v) { return v > 0.f ? v : 0.2f * v; }

// async global->LDS, 16B per lane. LDS dest must be linear (uniform base + lane*16).
__device__ __forceinline__ void gl_lds16(const void* g, void* l) {
  __builtin_amdgcn_global_load_lds(
      (const __attribute__((address_space(1))) unsigned int*)g,
      (__attribute__((address_space(3))) unsigned int*)l, 16, 0, 0);
}

// ---------------- device helpers ----------------

__device__ __forceinline__ void dev_transpose(const float* __restrict__ W,
                                              u16* __restrict__ WT,
                                              int K, int Nt, int bx, int by, int t) {
  __shared__ float s[32][33];
  const int kt = by * 32, nt = bx * 32;
  const int tx = t & 31, ty = t >> 5;   // (32,8)
#pragma unroll
  for (int i = 0; i < 32; i += 8)
    s[ty + i][tx] = W[(size_t)(kt + ty + i) * Nt + nt + tx];
  __syncthreads();
#pragma unroll
  for (int i = 0; i < 32; i += 8)
    WT[(size_t)(nt + ty + i) * K + kt + tx] = f2bf(s[tx][ty + i]);
}

// one wave computes pv for pair p=(k,h): pv[(h*2+sd)*K+k] = sum_c W[k][h*256+c]*a_sd[h][c]
__device__ __forceinline__ void dev_aproj(const float* __restrict__ W,
                                          const float* __restrict__ a_s,
                                          const float* __restrict__ a_d,
                                          float* __restrict__ pv, int K,
                                          int p, int ln) {
  const int h = p & 3, k = p >> 2;
  const float4 wv  = *(const float4*)(W + (size_t)k * DH + h * 256 + ln * 4);
  const float4 asv = *(const float4*)(a_s + h * 256 + ln * 4);
  const float4 adv = *(const float4*)(a_d + h * 256 + ln * 4);
  float ps = wv.x * asv.x + wv.y * asv.y + wv.z * asv.z + wv.w * asv.w;
  float pd = wv.x * adv.x + wv.y * adv.y + wv.z * adv.z + wv.w * adv.w;
#pragma unroll
  for (int off = 32; off; off >>= 1) {
    ps += __shfl_xor(ps, off);
    pd += __shfl_xor(pd, off);
  }
  if (ln == 0) {
    pv[(h * 2 + 0) * K + k] = ps;
    pv[(h * 2 + 1) * K + k] = pd;
  }
}

// one wave computes al_s/al_d for node n from its input row (K bf16) and pv[8][K]
template <int K>
__device__ __forceinline__ void dev_alv(const u16* __restrict__ rows,
                                        const float* __restrict__ pv,
                                        float* __restrict__ als,
                                        float* __restrict__ ald,
                                        int n, int ln) {
  constexpr int EPL = K / 64;   // elems per lane (8 or 16)
  float xr[EPL];
  const uint4* rp4 = (const uint4*)(rows + (size_t)n * K + ln * EPL);
#pragma unroll
  for (int q = 0; q < EPL / 8; q++) {
    uint4 hv = rp4[q];
    xr[q * 8 + 0] = bflo(hv.x); xr[q * 8 + 1] = bfhi(hv.x);
    xr[q * 8 + 2] = bflo(hv.y); xr[q * 8 + 3] = bfhi(hv.y);
    xr[q * 8 + 4] = bflo(hv.z); xr[q * 8 + 5] = bfhi(hv.z);
    xr[q * 8 + 6] = bflo(hv.w); xr[q * 8 + 7] = bfhi(hv.w);
  }
  float d[8];
#pragma unroll
  for (int v = 0; v < 8; v++) {
    const float* pvv = pv + v * K + ln * EPL;
    float s = 0.f;
#pragma unroll
    for (int j = 0; j < EPL; j++) s += xr[j] * pvv[j];
#pragma unroll
    for (int off = 32; off; off >>= 1) s += __shfl_xor(s, off);
    d[v] = s;
  }
  if (ln == 0) {
    als[n * 4 + 0] = d[0]; ald[n * 4 + 0] = d[1];
    als[n * 4 + 1] = d[2]; ald[n * 4 + 1] = d[3];
    als[n * 4 + 2] = d[4]; ald[n * 4 + 2] = d[5];
    als[n * 4 + 3] = d[6]; ald[n * 4 + 3] = d[7];
  }
}

// ---------------- merged prep: x->bf16, transposes, zeroing, aproj x2 ----------------

__global__ void k_prep(const float* __restrict__ x, u16* __restrict__ xb,
                       const float* __restrict__ W1, u16* __restrict__ w1t,
                       const float* __restrict__ W2, u16* __restrict__ w2t,
                       const float* __restrict__ Wfc, u16* __restrict__ wft,
                       int* __restrict__ indeg,
                       u16* __restrict__ hbp, u16* __restrict__ h2bp,
                       const float* __restrict__ as1, const float* __restrict__ ad1,
                       const float* __restrict__ as2, const float* __restrict__ ad2,
                       float* __restrict__ pv1, float* __restrict__ pv2) {
  int b = blockIdx.x, t = threadIdx.x;
  if (b < NB_CONV) {
    int i = b * 256 + t;
    float4 v = make_float4(0.f, 0.f, 0.f, 0.f);
    if (i < NND * DIN / 4) v = ((const float4*)x)[i];
    ushort4 o;
    o.x = f2bf(v.x); o.y = f2bf(v.y); o.z = f2bf(v.z); o.w = f2bf(v.w);
    ((ushort4*)xb)[i] = o;
    return;
  }
  b -= NB_CONV;
  if (b < NB_T1) { dev_transpose(W1, w1t, DIN, DH, b & 31, b >> 5, t); return; }
  b -= NB_T1;
  if (b < NB_T2) { dev_transpose(W2, w2t, DH, DH, b & 31, b >> 5, t); return; }
  b -= NB_T2;
  if (b < NB_T3) { dev_transpose(Wfc, wft, DH, DOUT, b & 15, b >> 4, t); return; }
  b -= NB_T3;
  if (b < NB_Z) {
    int i = b * 256 + t;
    const uint4 z = make_uint4(0, 0, 0, 0);
    if (i < (MP - NND) * DH / 8) { ((uint4*)hbp)[i] = z; ((uint4*)h2bp)[i] = z; }
    if (i < NND) indeg[i] = 0;
    return;
  }
  b -= NB_Z;
  if (b < NB_AP1) { dev_aproj(W1, as1, ad1, pv1, DIN, b * 4 + (t >> 6), t & 63); return; }
  b -= NB_AP1;
  { dev_aproj(W2, as2, ad2, pv2, DH, b * 4 + (t >> 6), t & 63); }
}

// ---------------- merged: CSR count + layer-1 attention logits ----------------

__global__ void k_cnt_alv(const int* __restrict__ ei, int* __restrict__ indeg,
                          const u16* __restrict__ xb, const float* __restrict__ pv1,
                          float* __restrict__ als1, float* __restrict__ ald1) {
  const int b = blockIdx.x, t = threadIdx.x;
  if (b < NB_CNT) {
    int e = b * 256 + t;
    if (e < NET) {
      int dst = (e < NED) ? ei[NED + e] : (e - NED);
      atomicAdd(&indeg[dst], 1);
    }
    return;
  }
  const int n = (b - NB_CNT) * 4 + (t >> 6);
  if (n < NND) dev_alv<DIN>(xb, pv1, als1, ald1, n, t & 63);
}

// layer-2 attention logits (standalone; depends on hb)
__global__ __launch_bounds__(64) void k_alv2(const u16* __restrict__ rows,
                                             const float* __restrict__ pv,
                                             float* __restrict__ als,
                                             float* __restrict__ ald) {
  dev_alv<DH>(rows, pv, als, ald, blockIdx.x, threadIdx.x);
}

// ---------------- CSR scan + fill ----------------

__global__ void k_scan1(const int* __restrict__ indeg, int* __restrict__ rowp,
                        int* __restrict__ bsum) {
  __shared__ int ws[4];
  const int b = blockIdx.x, t = threadIdx.x, wv = t >> 6, ln = t & 63;
  const int i = b * 256 + t;
  int v = (i < NND) ? indeg[i] : 0;
  int sc = v;
#pragma unroll
  for (int off = 1; off < 64; off <<= 1) {
    int xx = __shfl_up(sc, off);
    if (ln >= off) sc += xx;
  }
  if (ln == 63) ws[wv] = sc;
  __syncthreads();
  if (t == 0) {
    int a = 0;
#pragma unroll
    for (int k = 0; k < 4; k++) { int tmp = ws[k]; ws[k] = a; a += tmp; }
    bsum[b] = a;
  }
  __syncthreads();
  sc += ws[wv];
  if (i < NND) rowp[i + 1] = sc;   // block-local inclusive
}

__global__ void k_scan2(int* __restrict__ bsum) {   // 1 block, 64 threads
  int t = threadIdx.x;
  int v = (t < SCB) ? bsum[t] : 0;
  int sc = v;
#pragma unroll
  for (int off = 1; off < 64; off <<= 1) {
    int xx = __shfl_up(sc, off);
    if (t >= off) sc += xx;
  }
  if (t < SCB) bsum[t] = sc - v;   // exclusive
}

__global__ void k_scan3(int* __restrict__ rowp, const int* __restrict__ bsum,
                        int* __restrict__ cursor) {
  const int b = blockIdx.x, t = threadIdx.x;
  const int i = b * 256 + t;
  if (i < NND) { rowp[i + 1] += bsum[b]; cursor[i] = 0; }
  if (i == 0) rowp[0] = 0;
}

__global__ void k_fill(const int* __restrict__ ei, const int* __restrict__ rowp,
                       int* __restrict__ cursor, int* __restrict__ colsrc) {
  int e = blockIdx.x * 256 + threadIdx.x;
  if (e >= NET) return;
  int src, dst;
  if (e < NED) { src = ei[e]; dst = ei[NED + e]; }
  else         { src = dst = e - NED; }
  int pos = rowp[dst] + atomicAdd(&cursor[dst], 1);
  colsrc[pos] = src;
}

// ---------------- GEMM: C[M][ldc] = A[M][KD] * BT[Nt][KD]^T (+bias) ----------------
// bf16 inputs, fp32 accum. Output bf16 (OUTBF) or fp32. 128x128 tile, BK=32,
// 4 waves, 16x16x32 MFMA, global_load_lds width-16 staging, XCD-chunked swizzle.
// LDS anti-bank-conflict: 16B-slot XOR swizzle (both-sides involution).

template <int KD, int GX, bool HAS_BIAS, bool GUARD, bool OUTBF>
__global__ __launch_bounds__(256) void k_gemm(const u16* __restrict__ A,
                                              const u16* __restrict__ BT,
                                              float* __restrict__ Cf,
                                              u16* __restrict__ Cb,
                                              const float* __restrict__ bias,
                                              int ldc, int mvalid) {
  __shared__ __align__(16) u16 As[128 * 32];
  __shared__ __align__(16) u16 Bs[128 * 32];
  const int tid = threadIdx.x;
  const int lane = tid & 63;
  const int w = tid >> 6;
  const int wr = w >> 1, wc = w & 1;
  const int l15 = lane & 15;
  const int kg = (lane >> 4) * 8;
  const int kgs = kg ^ (((l15 >> 1) & 3) * 8);   // swizzled read slot

  // XCD-chunked bijective swizzle (m204)
  const int nwg = GX * gridDim.y;
  const int bid = blockIdx.y * GX + blockIdx.x;
  const int q = nwg >> 3, r = nwg & 7;
  const int xcd = bid & 7, idx = bid >> 3;
  const int swz = (xcd < r ? xcd * (q + 1) : r * (q + 1) + (xcd - r) * q) + idx;
  const int mt = swz / GX, nt = swz % GX;

  const int flat0 = tid * 8;
  const int row0 = tid >> 2;                         // rows 0..63 (chunk 0)
  const int kk0 = (((tid & 3) ^ ((tid >> 3) & 3)) * 8);  // swizzled source slot
  const int row1 = 64 + row0;                        // chunk 1; same (row>>1)&3

  const u16* Ab = A + (size_t)(mt * 128) * KD;
  const u16* Bb = BT + (size_t)(nt * 128) * KD;
  const u16* ga0 = Ab + row0 * KD + kk0;
  const u16* ga1 = Ab + row1 * KD + kk0;
  const u16* gb0 = Bb + row0 * KD + kk0;
  const u16* gb1 = Bb + row1 * KD + kk0;
  u16* lA0 = As + flat0;
  u16* lA1 = As + 2048 + flat0;
  u16* lB0 = Bs + flat0;
  u16* lB1 = Bs + 2048 + flat0;

  f32x4_t acc[4][4];
#pragma unroll
  for (int i = 0; i < 4; i++)
#pragma unroll
    for (int j = 0; j < 4; j++)
#pragma unroll
      for (int q2 = 0; q2 < 4; q2++) acc[i][j][q2] = 0.f;

  for (int kt = 0; kt < KD; kt += 32) {
    __syncthreads();
    gl_lds16(ga0 + kt, lA0);
    gl_lds16(ga1 + kt, lA1);
    gl_lds16(gb0 + kt, lB0);
    gl_lds16(gb1 + kt, lB1);
    __syncthreads();
    short8_t af[4], bfr[4];
#pragma unroll
    for (int i = 0; i < 4; i++)
      af[i] = *(const short8_t*)(As + (wr * 64 + i * 16 + l15) * 32 + kgs);
#pragma unroll
    for (int i = 0; i < 4; i++)
      bfr[i] = *(const short8_t*)(Bs + (wc * 64 + i * 16 + l15) * 32 + kgs);
#pragma unroll
    for (int i = 0; i < 4; i++)
#pragma unroll
      for (int j = 0; j < 4; j++)
        acc[i][j] = __builtin_amdgcn_mfma_f32_16x16x32_bf16(af[i], bfr[j], acc[i][j], 0, 0, 0);
  }

  const int rbase = mt * 128 + wr * 64 + (lane >> 4) * 4;
  const int cbase = nt * 128 + wc * 64 + l15;
#pragma unroll
  for (int i = 0; i < 4; i++) {
#pragma unroll
    for (int j = 0; j < 4; j++) {
#pragma unroll
      for (int q2 = 0; q2 < 4; q2++) {
        int rr = rbase + i * 16 + q2;
        int cc = cbase + j * 16;
        if (!GUARD || rr < mvalid) {
          float v = acc[i][j][q2];
          if (HAS_BIAS) v += bias[cc];
          if (OUTBF) Cb[(size_t)rr * ldc + cc] = f2bf(v);
          else       Cf[(size_t)rr * ldc + cc] = v;
        }
      }
    }
  }
}

// ---------------- fused segment-softmax + gather: one wave per (dst, head-quarter) ----------------
// Quarter q covers channels [q*256,(q+1)*256) == head q, so the whole wave shares one head.
// pass 1: full-wave max (stride 64 covers all edges for the single head).
// pass 2: accumulate sum(w*h), sum(w) with w=exp inline; 8B loads (512B/edge/wave).
// Slice footprint 5.2 MB ~ per-XCD L2 -> capacity misses shrink.

__global__ __launch_bounds__(64) void k_agg4(const u16* __restrict__ hprojb,
                                             const float* __restrict__ als,
                                             const float* __restrict__ ald,
                                             const int* __restrict__ rowp,
                                             const int* __restrict__ colsrc,
                                             const float* __restrict__ bias,
                                             u16* __restrict__ outb) {
  const int n = blockIdx.x, qh = blockIdx.y, ln = threadIdx.x;   // qh = head = quarter
  const int beg = rowp[n], end = rowp[n + 1];
  const float adv = ald[n * 4 + qh];

  // pass 1: max of leaky_relu(al_s[src]+al_d[n]) for head qh
  float m = -1e30f;
  for (int e = beg + ln; e < end; e += 64)
    m = fmaxf(m, lrelu(als[colsrc[e] * 4 + qh] + adv));
#pragma unroll
  for (int off = 32; off; off >>= 1) m = fmaxf(m, __shfl_xor(m, off));

  // pass 2: gather with inline softmax weight; 4 channels per lane (8B)
  const u16* hbase = hprojb + qh * 256 + ln * 4;
  float a0 = 0.f, a1 = 0.f, a2 = 0.f, a3 = 0.f;
  float ds = 0.f;
  int e = beg;
  for (; e + 1 < end; e += 2) {
    int s0 = colsrc[e], s1 = colsrc[e + 1];
    float w0 = __expf(lrelu(als[s0 * 4 + qh] + adv) - m);
    float w1 = __expf(lrelu(als[s1 * 4 + qh] + adv) - m);
    uint2 h0 = *(const uint2*)(hbase + (size_t)s0 * DH);
    uint2 h1 = *(const uint2*)(hbase + (size_t)s1 * DH);
    a0 += bflo(h0.x) * w0; a1 += bfhi(h0.x) * w0;
    a2 += bflo(h0.y) * w0; a3 += bfhi(h0.y) * w0;
    a0 += bflo(h1.x) * w1; a1 += bfhi(h1.x) * w1;
    a2 += bflo(h1.y) * w1; a3 += bfhi(h1.y) * w1;
    ds += w0 + w1;
  }
  if (e < end) {
    int s0 = colsrc[e];
    float w0 = __expf(lrelu(als[s0 * 4 + qh] + adv) - m);
    uint2 h0 = *(const uint2*)(hbase + (size_t)s0 * DH);
    a0 += bflo(h0.x) * w0; a1 += bfhi(h0.x) * w0;
    a2 += bflo(h0.y) * w0; a3 += bfhi(h0.y) * w0;
    ds += w0;
  }

  const float inv = 1.f / ds;
  const float4 bv = *(const float4*)(bias + qh * 256 + ln * 4);
  float o0 = fmaxf(a0 * inv + bv.x, 0.f), o1 = fmaxf(a1 * inv + bv.y, 0.f);
  float o2 = fmaxf(a2 * inv + bv.z, 0.f), o3 = fmaxf(a3 * inv + bv.w, 0.f);
  uint2 ob;
  ob.x = (unsigned)f2bf(o0) | ((unsigned)f2bf(o1) << 16);
  ob.y = (unsigned)f2bf(o2) | ((unsigned)f2bf(o3) << 16);
  *(uint2*)(outb + (size_t)n * DH + qh * 256 + ln * 4) = ob;
}

// ---------------- launcher ----------------

extern "C" void kernel_launch(void* const* d_in, const int* in_sizes, int n_in,
                              void* d_out, int out_size, void* d_ws, size_t ws_size,
                              hipStream_t stream) {
  const float* x   = (const float*)d_in[0];
  const int*   ei  = (const int*)d_in[1];
  const float* W1  = (const float*)d_in[2];
  const float* as1 = (const float*)d_in[3];
  const float* ad1 = (const float*)d_in[4];
  const float* b1  = (const float*)d_in[5];
  const float* W2  = (const float*)d_in[6];
  const float* as2 = (const float*)d_in[7];
  const float* ad2 = (const float*)d_in[8];
  const float* b2  = (const float*)d_in[9];
  const float* Wfc = (const float*)d_in[10];
  const float* bfc = (const float*)d_in[11];
  float* out = (float*)d_out;
  (void)in_sizes; (void)n_in; (void)out_size; (void)ws_size;

  // workspace carve
  char* p = (char*)d_ws;
  auto carve = [&](size_t bytes) -> char* {
    char* r = p; p += (bytes + 255) & ~(size_t)255; return r;
  };
  u16*   xb     = (u16*)  carve((size_t)MP * DIN * 2);
  u16*   w1t    = (u16*)  carve((size_t)DH * DIN * 2);
  u16*   w2t    = (u16*)  carve((size_t)DH * DH * 2);
  u16*   wft    = (u16*)  carve((size_t)DOUT * DH * 2);
  u16*   hprojb = (u16*)  carve((size_t)MP * DH * 2);
  u16*   hb     = (u16*)  carve((size_t)MP * DH * 2);
  u16*   h2b    = (u16*)  carve((size_t)MP * DH * 2);
  float* als1   = (float*)carve((size_t)NND * 4 * 4);
  float* ald1   = (float*)carve((size_t)NND * 4 * 4);
  float* als2   = (float*)carve((size_t)NND * 4 * 4);
  float* ald2   = (float*)carve((size_t)NND * 4 * 4);
  float* pv1    = (float*)carve((size_t)8 * DIN * 4);
  float* pv2    = (float*)carve((size_t)8 * DH * 4);
  int*   indeg  = (int*)  carve((size_t)NND * 4);
  int*   rowp   = (int*)  carve((size_t)(NND + 1) * 4);
  int*   cursor = (int*)  carve((size_t)NND * 4);
  int*   colsrc = (int*)  carve((size_t)NET * 4);
  int*   bsum   = (int*)  carve((size_t)SCB * 4);

  // prep (conv_x + transposes + zero + aproj x2), then CSR (+ fused alv1)
  k_prep<<<NB_PREP, 256, 0, stream>>>(x, xb, W1, w1t, W2, w2t, Wfc, wft,
      indeg, hb + (size_t)NND * DH, h2b + (size_t)NND * DH,
      as1, ad1, as2, ad2, pv1, pv2);
  k_cnt_alv<<<NB_CNT + NB_ALV1, 256, 0, stream>>>(ei, indeg, xb, pv1, als1, ald1);
  k_scan1<<<SCB, 256, 0, stream>>>(indeg, rowp, bsum);
  k_scan2<<<1, 64, 0, stream>>>(bsum);
  k_scan3<<<SCB, 256, 0, stream>>>(rowp, bsum, cursor);
  k_fill<<<(NET + 255) / 256, 256, 0, stream>>>(ei, rowp, cursor, colsrc);

  // layer 1
  k_gemm<DIN, 8, false, false, true><<<dim3(DH / 128, MP / 128), 256, 0, stream>>>(
      xb, w1t, nullptr, hprojb, nullptr, DH, MP);
  k_agg4<<<dim3(NND, 4), 64, 0, stream>>>(hprojb, als1, ald1, rowp, colsrc, b1, hb);

  // layer 2
  k_alv2<<<NND, 64, 0, stream>>>(hb, pv2, als2, ald2);
  k_gemm<DH, 8, false, false, true><<<dim3(DH / 128, MP / 128), 256, 0, stream>>>(
      hb, w2t, nullptr, hprojb, nullptr, DH, MP);
  k_agg4<<<dim3(NND, 4), 64, 0, stream>>>(hprojb, als2, ald2, rowp, colsrc, b2, h2b);

  // FC
  k_gemm<DH, 4, true, true, false><<<dim3(DOUT / 128, MP / 128), 256, 0, stream>>>(
      h2b, wft, out, nullptr, bfc, DOUT, NND);
}

// Round 10
// 210.361 us; speedup vs baseline: 1.5910x; 1.0798x over previous
//
#include <hip/hip_runtime.h>

// Problem constants
#define NND 10000      // nodes
#define NED 160000     // edges (before self loops)
#define NET 170000     // edges incl self loops
#define MP  10112      // node rows padded to multiple of 128 (79*128)
#define DH  1024       // H*C hidden width
#define DIN 512
#define DOUT 512
#define SCB 40         // scan blocks: ceil(NND/256)

// prep kernel block ranges
#define NB_CONV 5056   // MP*DIN/4/256
#define NB_T1   512    // (DH/32)*(DIN/32)
#define NB_T2   1024   // (DH/32)*(DH/32)
#define NB_T3   512    // (DOUT/32)*(DH/32)
#define NB_Z    80
#define NB_AP1  512    // DIN*4/4 pairs-per-block
#define NB_AP2  1024   // DH*4/4
#define NB_PREP (NB_CONV + NB_T1 + NB_T2 + NB_T3 + NB_Z + NB_AP1 + NB_AP2)

// count+alv1 merged kernel
#define NB_CNT  665    // ceil(NET/256)
#define NB_ALV1 2500   // NND/4 (4 waves per block, 1 node per wave)

typedef unsigned short u16;
typedef __attribute__((ext_vector_type(8))) short short8_t;
typedef __attribute__((ext_vector_type(4))) float f32x4_t;

__device__ __forceinline__ u16 f2bf(float f) {
  unsigned u = __float_as_uint(f);
  return (u16)((u + 0x7fffu + ((u >> 16) & 1u)) >> 16);
}
__device__ __forceinline__ float bf2f(u16 b) {
  return __uint_as_float(((unsigned)b) << 16);
}
__device__ __forceinline__ float bflo(unsigned u) { return __uint_as_float(u << 16); }
__device__ __forceinline__ float bfhi(unsigned u) { return __uint_as_float(u & 0xffff0000u); }
__device__ __forceinline__ float lrelu(float v) { return v > 0.f ? v : 0.2f * v; }

// async global->LDS, 16B per lane. LDS dest must be linear (uniform base + lane*16).
__device__ __forceinline__ void gl_lds16(const void* g, void* l) {
  __builtin_amdgcn_global_load_lds(
      (const __attribute__((address_space(1))) unsigned int*)g,
      (__attribute__((address_space(3))) unsigned int*)l, 16, 0, 0);
}

// ---------------- device helpers ----------------

__device__ __forceinline__ void dev_transpose(const float* __restrict__ W,
                                              u16* __restrict__ WT,
                                              int K, int Nt, int bx, int by, int t) {
  __shared__ float s[32][33];
  const int kt = by * 32, nt = bx * 32;
  const int tx = t & 31, ty = t >> 5;   // (32,8)
#pragma unroll
  for (int i = 0; i < 32; i += 8)
    s[ty + i][tx] = W[(size_t)(kt + ty + i) * Nt + nt + tx];
  __syncthreads();
#pragma unroll
  for (int i = 0; i < 32; i += 8)
    WT[(size_t)(nt + ty + i) * K + kt + tx] = f2bf(s[tx][ty + i]);
}

// one wave computes pv for pair p=(k,h): pv[(h*2+sd)*K+k] = sum_c W[k][h*256+c]*a_sd[h][c]
__device__ __forceinline__ void dev_aproj(const float* __restrict__ W,
                                          const float* __restrict__ a_s,
                                          const float* __restrict__ a_d,
                                          float* __restrict__ pv, int K,
                                          int p, int ln) {
  const int h = p & 3, k = p >> 2;
  const float4 wv  = *(const float4*)(W + (size_t)k * DH + h * 256 + ln * 4);
  const float4 asv = *(const float4*)(a_s + h * 256 + ln * 4);
  const float4 adv = *(const float4*)(a_d + h * 256 + ln * 4);
  float ps = wv.x * asv.x + wv.y * asv.y + wv.z * asv.z + wv.w * asv.w;
  float pd = wv.x * adv.x + wv.y * adv.y + wv.z * adv.z + wv.w * adv.w;
#pragma unroll
  for (int off = 32; off; off >>= 1) {
    ps += __shfl_xor(ps, off);
    pd += __shfl_xor(pd, off);
  }
  if (ln == 0) {
    pv[(h * 2 + 0) * K + k] = ps;
    pv[(h * 2 + 1) * K + k] = pd;
  }
}

// one wave computes al_s/al_d for node n from its input row (K bf16) and pv[8][K]
template <int K>
__device__ __forceinline__ void dev_alv(const u16* __restrict__ rows,
                                        const float* __restrict__ pv,
                                        float* __restrict__ als,
                                        float* __restrict__ ald,
                                        int n, int ln) {
  constexpr int EPL = K / 64;   // elems per lane (8 or 16)
  float xr[EPL];
  const uint4* rp4 = (const uint4*)(rows + (size_t)n * K + ln * EPL);
#pragma unroll
  for (int q = 0; q < EPL / 8; q++) {
    uint4 hv = rp4[q];
    xr[q * 8 + 0] = bflo(hv.x); xr[q * 8 + 1] = bfhi(hv.x);
    xr[q * 8 + 2] = bflo(hv.y); xr[q * 8 + 3] = bfhi(hv.y);
    xr[q * 8 + 4] = bflo(hv.z); xr[q * 8 + 5] = bfhi(hv.z);
    xr[q * 8 + 6] = bflo(hv.w); xr[q * 8 + 7] = bfhi(hv.w);
  }
  float d[8];
#pragma unroll
  for (int v = 0; v < 8; v++) {
    const float* pvv = pv + v * K + ln * EPL;
    float s = 0.f;
#pragma unroll
    for (int j = 0; j < EPL; j++) s += xr[j] * pvv[j];
#pragma unroll
    for (int off = 32; off; off >>= 1) s += __shfl_xor(s, off);
    d[v] = s;
  }
  if (ln == 0) {
    als[n * 4 + 0] = d[0]; ald[n * 4 + 0] = d[1];
    als[n * 4 + 1] = d[2]; ald[n * 4 + 1] = d[3];
    als[n * 4 + 2] = d[4]; ald[n * 4 + 2] = d[5];
    als[n * 4 + 3] = d[6]; ald[n * 4 + 3] = d[7];
  }
}

// ---------------- merged prep: x->bf16, transposes, zeroing, aproj x2 ----------------

__global__ void k_prep(const float* __restrict__ x, u16* __restrict__ xb,
                       const float* __restrict__ W1, u16* __restrict__ w1t,
                       const float* __restrict__ W2, u16* __restrict__ w2t,
                       const float* __restrict__ Wfc, u16* __restrict__ wft,
                       int* __restrict__ indeg,
                       u16* __restrict__ hbp, u16* __restrict__ h2bp,
                       const float* __restrict__ as1, const float* __restrict__ ad1,
                       const float* __restrict__ as2, const float* __restrict__ ad2,
                       float* __restrict__ pv1, float* __restrict__ pv2,
                       float* __restrict__ als2, float* __restrict__ ald2) {
  int b = blockIdx.x, t = threadIdx.x;
  if (b < NB_CONV) {
    int i = b * 256 + t;
    float4 v = make_float4(0.f, 0.f, 0.f, 0.f);
    if (i < NND * DIN / 4) v = ((const float4*)x)[i];
    ushort4 o;
    o.x = f2bf(v.x); o.y = f2bf(v.y); o.z = f2bf(v.z); o.w = f2bf(v.w);
    ((ushort4*)xb)[i] = o;
    return;
  }
  b -= NB_CONV;
  if (b < NB_T1) { dev_transpose(W1, w1t, DIN, DH, b & 31, b >> 5, t); return; }
  b -= NB_T1;
  if (b < NB_T2) { dev_transpose(W2, w2t, DH, DH, b & 31, b >> 5, t); return; }
  b -= NB_T2;
  if (b < NB_T3) { dev_transpose(Wfc, wft, DH, DOUT, b & 15, b >> 4, t); return; }
  b -= NB_T3;
  if (b < NB_Z) {
    int i = b * 256 + t;
    const uint4 z = make_uint4(0, 0, 0, 0);
    if (i < (MP - NND) * DH / 8) { ((uint4*)hbp)[i] = z; ((uint4*)h2bp)[i] = z; }
    if (i < NND) {
      indeg[i] = 0;
      const float4 zf = make_float4(0.f, 0.f, 0.f, 0.f);
      ((float4*)als2)[i] = zf;   // accumulated by layer-1 agg epilogue
      ((float4*)ald2)[i] = zf;
    }
    return;
  }
  b -= NB_Z;
  if (b < NB_AP1) { dev_aproj(W1, as1, ad1, pv1, DIN, b * 4 + (t >> 6), t & 63); return; }
  b -= NB_AP1;
  { dev_aproj(W2, as2, ad2, pv2, DH, b * 4 + (t >> 6), t & 63); }
}

// ---------------- merged: CSR count + layer-1 attention logits ----------------

__global__ void k_cnt_alv(const int* __restrict__ ei, int* __restrict__ indeg,
                          const u16* __restrict__ xb, const float* __restrict__ pv1,
                          float* __restrict__ als1, float* __restrict__ ald1) {
  const int b = blockIdx.x, t = threadIdx.x;
  if (b < NB_CNT) {
    int e = b * 256 + t;
    if (e < NET) {
      int dst = (e < NED) ? ei[NED + e] : (e - NED);
      atomicAdd(&indeg[dst], 1);
    }
    return;
  }
  const int n = (b - NB_CNT) * 4 + (t >> 6);
  if (n < NND) dev_alv<DIN>(xb, pv1, als1, ald1, n, t & 63);
}

// ---------------- CSR scan + fill ----------------

__global__ void k_scan1(const int* __restrict__ indeg, int* __restrict__ rowp,
                        int* __restrict__ bsum) {
  __shared__ int ws[4];
  const int b = blockIdx.x, t = threadIdx.x, wv = t >> 6, ln = t & 63;
  const int i = b * 256 + t;
  int v = (i < NND) ? indeg[i] : 0;
  int sc = v;
#pragma unroll
  for (int off = 1; off < 64; off <<= 1) {
    int xx = __shfl_up(sc, off);
    if (ln >= off) sc += xx;
  }
  if (ln == 63) ws[wv] = sc;
  __syncthreads();
  if (t == 0) {
    int a = 0;
#pragma unroll
    for (int k = 0; k < 4; k++) { int tmp = ws[k]; ws[k] = a; a += tmp; }
    bsum[b] = a;
  }
  __syncthreads();
  sc += ws[wv];
  if (i < NND) rowp[i + 1] = sc;   // block-local inclusive
}

__global__ void k_scan2(int* __restrict__ bsum) {   // 1 block, 64 threads
  int t = threadIdx.x;
  int v = (t < SCB) ? bsum[t] : 0;
  int sc = v;
#pragma unroll
  for (int off = 1; off < 64; off <<= 1) {
    int xx = __shfl_up(sc, off);
    if (t >= off) sc += xx;
  }
  if (t < SCB) bsum[t] = sc - v;   // exclusive
}

__global__ void k_scan3(int* __restrict__ rowp, const int* __restrict__ bsum,
                        int* __restrict__ cursor) {
  const int b = blockIdx.x, t = threadIdx.x;
  const int i = b * 256 + t;
  if (i < NND) { rowp[i + 1] += bsum[b]; cursor[i] = 0; }
  if (i == 0) rowp[0] = 0;
}

__global__ void k_fill(const int* __restrict__ ei, const int* __restrict__ rowp,
                       int* __restrict__ cursor, int* __restrict__ colsrc) {
  int e = blockIdx.x * 256 + threadIdx.x;
  if (e >= NET) return;
  int src, dst;
  if (e < NED) { src = ei[e]; dst = ei[NED + e]; }
  else         { src = dst = e - NED; }
  int pos = rowp[dst] + atomicAdd(&cursor[dst], 1);
  colsrc[pos] = src;
}

// ---------------- GEMM: C[M][ldc] = A[M][KD] * BT[Nt][KD]^T (+bias) ----------------
// bf16 inputs, fp32 accum. Output bf16 (OUTBF) or fp32. 128x128 tile, BK=32,
// 4 waves, 16x16x32 MFMA, global_load_lds width-16 staging, XCD-chunked swizzle.
// LDS anti-bank-conflict: 16B-slot XOR swizzle (both-sides involution).

template <int KD, int GX, bool HAS_BIAS, bool GUARD, bool OUTBF>
__global__ __launch_bounds__(256) void k_gemm(const u16* __restrict__ A,
                                              const u16* __restrict__ BT,
                                              float* __restrict__ Cf,
                                              u16* __restrict__ Cb,
                                              const float* __restrict__ bias,
                                              int ldc, int mvalid) {
  __shared__ __align__(16) u16 As[128 * 32];
  __shared__ __align__(16) u16 Bs[128 * 32];
  const int tid = threadIdx.x;
  const int lane = tid & 63;
  const int w = tid >> 6;
  const int wr = w >> 1, wc = w & 1;
  const int l15 = lane & 15;
  const int kg = (lane >> 4) * 8;
  const int kgs = kg ^ (((l15 >> 1) & 3) * 8);   // swizzled read slot

  // XCD-chunked bijective swizzle (m204)
  const int nwg = GX * gridDim.y;
  const int bid = blockIdx.y * GX + blockIdx.x;
  const int q = nwg >> 3, r = nwg & 7;
  const int xcd = bid & 7, idx = bid >> 3;
  const int swz = (xcd < r ? xcd * (q + 1) : r * (q + 1) + (xcd - r) * q) + idx;
  const int mt = swz / GX, nt = swz % GX;

  const int flat0 = tid * 8;
  const int row0 = tid >> 2;                         // rows 0..63 (chunk 0)
  const int kk0 = (((tid & 3) ^ ((tid >> 3) & 3)) * 8);  // swizzled source slot
  const int row1 = 64 + row0;                        // chunk 1; same (row>>1)&3

  const u16* Ab = A + (size_t)(mt * 128) * KD;
  const u16* Bb = BT + (size_t)(nt * 128) * KD;
  const u16* ga0 = Ab + row0 * KD + kk0;
  const u16* ga1 = Ab + row1 * KD + kk0;
  const u16* gb0 = Bb + row0 * KD + kk0;
  const u16* gb1 = Bb + row1 * KD + kk0;
  u16* lA0 = As + flat0;
  u16* lA1 = As + 2048 + flat0;
  u16* lB0 = Bs + flat0;
  u16* lB1 = Bs + 2048 + flat0;

  f32x4_t acc[4][4];
#pragma unroll
  for (int i = 0; i < 4; i++)
#pragma unroll
    for (int j = 0; j < 4; j++)
#pragma unroll
      for (int q2 = 0; q2 < 4; q2++) acc[i][j][q2] = 0.f;

  for (int kt = 0; kt < KD; kt += 32) {
    __syncthreads();
    gl_lds16(ga0 + kt, lA0);
    gl_lds16(ga1 + kt, lA1);
    gl_lds16(gb0 + kt, lB0);
    gl_lds16(gb1 + kt, lB1);
    __syncthreads();
    short8_t af[4], bfr[4];
#pragma unroll
    for (int i = 0; i < 4; i++)
      af[i] = *(const short8_t*)(As + (wr * 64 + i * 16 + l15) * 32 + kgs);
#pragma unroll
    for (int i = 0; i < 4; i++)
      bfr[i] = *(const short8_t*)(Bs + (wc * 64 + i * 16 + l15) * 32 + kgs);
#pragma unroll
    for (int i = 0; i < 4; i++)
#pragma unroll
      for (int j = 0; j < 4; j++)
        acc[i][j] = __builtin_amdgcn_mfma_f32_16x16x32_bf16(af[i], bfr[j], acc[i][j], 0, 0, 0);
  }

  const int rbase = mt * 128 + wr * 64 + (lane >> 4) * 4;
  const int cbase = nt * 128 + wc * 64 + l15;
#pragma unroll
  for (int i = 0; i < 4; i++) {
#pragma unroll
    for (int j = 0; j < 4; j++) {
#pragma unroll
      for (int q2 = 0; q2 < 4; q2++) {
        int rr = rbase + i * 16 + q2;
        int cc = cbase + j * 16;
        if (!GUARD || rr < mvalid) {
          float v = acc[i][j][q2];
          if (HAS_BIAS) v += bias[cc];
          if (OUTBF) Cb[(size_t)rr * ldc + cc] = f2bf(v);
          else       Cf[(size_t)rr * ldc + cc] = v;
        }
      }
    }
  }
}

// ---------------- fused segment-softmax + gather: one wave per (dst, ch-half) ----------------
// No max pre-pass: |logits| << 88 so exp is fp32-safe; softmax ratio is shift-invariant.
// 16B h loads (8 ch/lane), 4-edge unroll for MLP. Optional epilogue (FUSE_ALV):
// partial dots of the relu'd output with pv2 -> atomicAdd into als2/ald2 (layer-2 logits).

template <bool FUSE_ALV>
__global__ __launch_bounds__(64) void k_aggh(const u16* __restrict__ hprojb,
                                             const float* __restrict__ als,
                                             const float* __restrict__ ald,
                                             const int* __restrict__ rowp,
                                             const int* __restrict__ colsrc,
                                             const float* __restrict__ bias,
                                             u16* __restrict__ outb,
                                             const float* __restrict__ pv2,
                                             float* __restrict__ als2,
                                             float* __restrict__ ald2) {
  const int n = blockIdx.x, half = blockIdx.y, ln = threadIdx.x;
  const int beg = rowp[n], end = rowp[n + 1];
  const int hsel = 2 * half + (ln >> 5);          // head for this lane's 8 channels
  const float adv = ald[n * 4 + hsel];
  const u16* hbase = hprojb + half * 512 + ln * 8;

  float a0 = 0.f, a1 = 0.f, a2 = 0.f, a3 = 0.f;
  float a4 = 0.f, a5 = 0.f, a6 = 0.f, a7 = 0.f;
  float ds = 0.f;
  int e = beg;
  for (; e + 3 < end; e += 4) {
    int s0 = colsrc[e], s1 = colsrc[e + 1], s2 = colsrc[e + 2], s3 = colsrc[e + 3];
    float l0 = als[s0 * 4 + hsel], l1 = als[s1 * 4 + hsel];
    float l2 = als[s2 * 4 + hsel], l3 = als[s3 * 4 + hsel];
    uint4 h0 = *(const uint4*)(hbase + (size_t)s0 * DH);
    uint4 h1 = *(const uint4*)(hbase + (size_t)s1 * DH);
    uint4 h2 = *(const uint4*)(hbase + (size_t)s2 * DH);
    uint4 h3 = *(const uint4*)(hbase + (size_t)s3 * DH);
    float w0 = __expf(lrelu(l0 + adv)), w1 = __expf(lrelu(l1 + adv));
    float w2 = __expf(lrelu(l2 + adv)), w3 = __expf(lrelu(l3 + adv));
    a0 += bflo(h0.x) * w0; a1 += bfhi(h0.x) * w0;
    a2 += bflo(h0.y) * w0; a3 += bfhi(h0.y) * w0;
    a4 += bflo(h0.z) * w0; a5 += bfhi(h0.z) * w0;
    a6 += bflo(h0.w) * w0; a7 += bfhi(h0.w) * w0;
    a0 += bflo(h1.x) * w1; a1 += bfhi(h1.x) * w1;
    a2 += bflo(h1.y) * w1; a3 += bfhi(h1.y) * w1;
    a4 += bflo(h1.z) * w1; a5 += bfhi(h1.z) * w1;
    a6 += bflo(h1.w) * w1; a7 += bfhi(h1.w) * w1;
    a0 += bflo(h2.x) * w2; a1 += bfhi(h2.x) * w2;
    a2 += bflo(h2.y) * w2; a3 += bfhi(h2.y) * w2;
    a4 += bflo(h2.z) * w2; a5 += bfhi(h2.z) * w2;
    a6 += bflo(h2.w) * w2; a7 += bfhi(h2.w) * w2;
    a0 += bflo(h3.x) * w3; a1 += bfhi(h3.x) * w3;
    a2 += bflo(h3.y) * w3; a3 += bfhi(h3.y) * w3;
    a4 += bflo(h3.z) * w3; a5 += bfhi(h3.z) * w3;
    a6 += bflo(h3.w) * w3; a7 += bfhi(h3.w) * w3;
    ds += (w0 + w1) + (w2 + w3);
  }
  for (; e < end; e++) {
    int s0 = colsrc[e];
    float w0 = __expf(lrelu(als[s0 * 4 + hsel] + adv));
    uint4 h0 = *(const uint4*)(hbase + (size_t)s0 * DH);
    a0 += bflo(h0.x) * w0; a1 += bfhi(h0.x) * w0;
    a2 += bflo(h0.y) * w0; a3 += bfhi(h0.y) * w0;
    a4 += bflo(h0.z) * w0; a5 += bfhi(h0.z) * w0;
    a6 += bflo(h0.w) * w0; a7 += bfhi(h0.w) * w0;
    ds += w0;
  }

  const float inv = 1.f / ds;
  const float4 bv0 = *(const float4*)(bias + half * 512 + ln * 8);
  const float4 bv1 = *(const float4*)(bias + half * 512 + ln * 8 + 4);
  float o0 = fmaxf(a0 * inv + bv0.x, 0.f), o1 = fmaxf(a1 * inv + bv0.y, 0.f);
  float o2 = fmaxf(a2 * inv + bv0.z, 0.f), o3 = fmaxf(a3 * inv + bv0.w, 0.f);
  float o4 = fmaxf(a4 * inv + bv1.x, 0.f), o5 = fmaxf(a5 * inv + bv1.y, 0.f);
  float o6 = fmaxf(a6 * inv + bv1.z, 0.f), o7 = fmaxf(a7 * inv + bv1.w, 0.f);
  uint4 ob;
  ob.x = (unsigned)f2bf(o0) | ((unsigned)f2bf(o1) << 16);
  ob.y = (unsigned)f2bf(o2) | ((unsigned)f2bf(o3) << 16);
  ob.z = (unsigned)f2bf(o4) | ((unsigned)f2bf(o5) << 16);
  ob.w = (unsigned)f2bf(o6) | ((unsigned)f2bf(o7) << 16);
  *(uint4*)(outb + (size_t)n * DH + half * 512 + ln * 8) = ob;

  if (FUSE_ALV) {
    // layer-2 logits: partial dot of this half-row with pv2[v][.], v = h'*2+sd
    const int cb = half * 512 + ln * 8;
    float ov[8] = {o0, o1, o2, o3, o4, o5, o6, o7};
#pragma unroll
    for (int v = 0; v < 8; v++) {
      const float* pvv = pv2 + (size_t)v * DH + cb;
      float s = ov[0] * pvv[0] + ov[1] * pvv[1] + ov[2] * pvv[2] + ov[3] * pvv[3] +
                ov[4] * pvv[4] + ov[5] * pvv[5] + ov[6] * pvv[6] + ov[7] * pvv[7];
#pragma unroll
      for (int off = 32; off; off >>= 1) s += __shfl_xor(s, off);
      if (ln == 0) {
        int h = v >> 1;
        if (v & 1) atomicAdd(&ald2[n * 4 + h], s);
        else       atomicAdd(&als2[n * 4 + h], s);
      }
    }
  }
}

// ---------------- launcher ----------------

extern "C" void kernel_launch(void* const* d_in, const int* in_sizes, int n_in,
                              void* d_out, int out_size, void* d_ws, size_t ws_size,
                              hipStream_t stream) {
  const float* x   = (const float*)d_in[0];
  const int*   ei  = (const int*)d_in[1];
  const float* W1  = (const float*)d_in[2];
  const float* as1 = (const float*)d_in[3];
  const float* ad1 = (const float*)d_in[4];
  const float* b1  = (const float*)d_in[5];
  const float* W2  = (const float*)d_in[6];
  const float* as2 = (const float*)d_in[7];
  const float* ad2 = (const float*)d_in[8];
  const float* b2  = (const float*)d_in[9];
  const float* Wfc = (const float*)d_in[10];
  const float* bfc = (const float*)d_in[11];
  float* out = (float*)d_out;
  (void)in_sizes; (void)n_in; (void)out_size; (void)ws_size;

  // workspace carve
  char* p = (char*)d_ws;
  auto carve = [&](size_t bytes) -> char* {
    char* r = p; p += (bytes + 255) & ~(size_t)255; return r;
  };
  u16*   xb     = (u16*)  carve((size_t)MP * DIN * 2);
  u16*   w1t    = (u16*)  carve((size_t)DH * DIN * 2);
  u16*   w2t    = (u16*)  carve((size_t)DH * DH * 2);
  u16*   wft    = (u16*)  carve((size_t)DOUT * DH * 2);
  u16*   hprojb = (u16*)  carve((size_t)MP * DH * 2);
  u16*   hb     = (u16*)  carve((size_t)MP * DH * 2);
  u16*   h2b    = (u16*)  carve((size_t)MP * DH * 2);
  float* als1   = (float*)carve((size_t)NND * 4 * 4);
  float* ald1   = (float*)carve((size_t)NND * 4 * 4);
  float* als2   = (float*)carve((size_t)NND * 4 * 4);
  float* ald2   = (float*)carve((size_t)NND * 4 * 4);
  float* pv1    = (float*)carve((size_t)8 * DIN * 4);
  float* pv2    = (float*)carve((size_t)8 * DH * 4);
  int*   indeg  = (int*)  carve((size_t)NND * 4);
  int*   rowp   = (int*)  carve((size_t)(NND + 1) * 4);
  int*   cursor = (int*)  carve((size_t)NND * 4);
  int*   colsrc = (int*)  carve((size_t)NET * 4);
  int*   bsum   = (int*)  carve((size_t)SCB * 4);

  // prep (conv_x + transposes + zero + aproj x2), then CSR (+ fused alv1)
  k_prep<<<NB_PREP, 256, 0, stream>>>(x, xb, W1, w1t, W2, w2t, Wfc, wft,
      indeg, hb + (size_t)NND * DH, h2b + (size_t)NND * DH,
      as1, ad1, as2, ad2, pv1, pv2, als2, ald2);
  k_cnt_alv<<<NB_CNT + NB_ALV1, 256, 0, stream>>>(ei, indeg, xb, pv1, als1, ald1);
  k_scan1<<<SCB, 256, 0, stream>>>(indeg, rowp, bsum);
  k_scan2<<<1, 64, 0, stream>>>(bsum);
  k_scan3<<<SCB, 256, 0, stream>>>(rowp, bsum, cursor);
  k_fill<<<(NET + 255) / 256, 256, 0, stream>>>(ei, rowp, cursor, colsrc);

  // layer 1 (agg epilogue computes layer-2 logits into als2/ald2)
  k_gemm<DIN, 8, false, false, true><<<dim3(DH / 128, MP / 128), 256, 0, stream>>>(
      xb, w1t, nullptr, hprojb, nullptr, DH, MP);
  k_aggh<true><<<dim3(NND, 2), 64, 0, stream>>>(hprojb, als1, ald1, rowp, colsrc,
      b1, hb, pv2, als2, ald2);

  // layer 2
  k_gemm<DH, 8, false, false, true><<<dim3(DH / 128, MP / 128), 256, 0, stream>>>(
      hb, w2t, nullptr, hprojb, nullptr, DH, MP);
  k_aggh<false><<<dim3(NND, 2), 64, 0, stream>>>(hprojb, als2, ald2, rowp, colsrc,
      b2, h2b, nullptr, nullptr, nullptr);

  // FC
  k_gemm<DH, 4, true, true, false><<<dim3(DOUT / 128, MP / 128), 256, 0, stream>>>(
      h2b, wft, out, nullptr, bfc, DOUT, NND);
}